// Round 9
// baseline (454.756 us; speedup 1.0000x reference)
//
#include <hip/hip_runtime.h>
#include <hip/hip_bf16.h>
#include <math.h>

// CFConv: out[a][f] = sum_n x[nbr[a][n]][f] * W[a][n][f]
//   W = (softplus(rbf @ w1 + b1)) @ w2 + b2
// N=20000 atoms, NB=32 neighbors, F=128, RBF=64.
//
// R9 = R7 (95us, VALU-issue-bound, 64-VGPR allocator ceiling accepted) with
// two VALU cuts inside the register envelope:
//  (1) bias folded into MFMA acc init (acc init movs exist anyway) -> kills
//      128 v_add/atom; GEMM2's +b2 distributes through the epilogue product.
//  (2) W never touches LDS: epilogue consumes GEMM2's acc in MFMA C-layout
//      (lane q,ln owns rows q*4+r, col nt*16+ln). Kills W pk2/pack (16),
//      swizzled W stores (32+addr), epilogue ds_reads+unpack (64), and the
//      W-write->read LDS dependency. Adds: 4 quad-uniform idx loads, 32
//      dword x-loads (4x64B segments, x is L2/L3-resident), 32 fma into
//      psum[8], per-half shfl_xor butterfly over quads. Net ~-300 instr/atom.
// Keeps: scale-folded softplus (log2e in w1/b1, ln2 in w2 -> sp2 = exp2+add+
// log2), swizzled H band, 80KB LDS = 2 blocks/CU, LDS_FENCE ordering.
// R3/R6/R8 lesson: spill shows as WRITE_SIZE >> 10MB -> revert trigger.

#define NB     32
#define FD     128
#define RD     64
#define WAVES  8
#define NTILES 2500   // 20000 / 8

#define LOG2E 1.4426950408889634f
#define LN2   0.6931471805599453f

typedef short  short8  __attribute__((ext_vector_type(8)));
typedef float  floatx4 __attribute__((ext_vector_type(4)));
typedef float  floatx2 __attribute__((ext_vector_type(2)));

#define LDS_FENCE() asm volatile("" ::: "memory")  // compiler-only ordering, no instr

static __device__ __forceinline__ unsigned pk2(float a, float b) {
  // packed fp32->bf16 RNE (v_cvt_pk_bf16_f32 on gfx950); low 16 = a
  __hip_bfloat162 h = __float22bfloat162_rn(float2{a, b});
  unsigned u;
  __builtin_memcpy(&u, &h, sizeof(u));
  return u;
}

// log2-domain softplus: log2e folded into GEMM1 operands, ln2 into w2.
static __device__ __forceinline__ float sp2(float acc) {
  return __builtin_amdgcn_logf(1.0f + __builtin_amdgcn_exp2f(acc));
}

__global__ __launch_bounds__(512, 4)  // R7's exact attributes (known-good 95us)
void cfconv_kernel(const float* __restrict__ x,
                   const float* __restrict__ rbf,
                   const int*   __restrict__ nbr,
                   const float* __restrict__ w1,
                   const float* __restrict__ b1,
                   const float* __restrict__ w2,
                   const float* __restrict__ b2,
                   float* __restrict__ out) {
  // B-fragment layout: frag[kt*8+nt][lane][j] = B[kt*32 + (lane>>4)*8 + j][nt*16 + (lane&15)]
  __shared__ __align__(16) short w1f[16][64][8];        // 16 KB
  __shared__ __align__(16) short w2f[32][64][8];        // 32 KB
  // per-wave 16-row x 128-col bf16 H staging; 16B-block XOR swizzle:
  // element (row, col) lives at band[row][ ((col>>3 ^ row)&15)*8 + (col&7) ]
  __shared__ __align__(16) short hbuf[WAVES * 16][128]; // 32 KB -> total exactly 80 KB

  const int tid  = threadIdx.x;
  const int lane = tid & 63;
  const int wv   = tid >> 6;
  const int q    = lane >> 4;   // k-quad (A/B) or row-quad (C)
  const int ln   = lane & 15;   // m (A/C row) or n (B/C col) inside a 16-tile

  // ---- prepack weights (with scale folding) -> bf16 B-frags in LDS ----
  for (int i = tid; i < RD * FD; i += 512) {
    int k = i >> 7, n = i & 127, kk = k & 31;
    w1f[(k >> 5) * 8 + (n >> 4)][(kk >> 3) * 16 + (n & 15)][kk & 7] =
        (short)pk2(w1[i] * LOG2E, 0.f);
  }
  for (int i = tid; i < FD * FD; i += 512) {
    int k = i >> 7, n = i & 127, kk = k & 31;
    w2f[(k >> 5) * 8 + (n >> 4)][(kk >> 3) * 16 + (n & 15)][kk & 7] =
        (short)pk2(w2[i] * LN2, 0.f);
  }
  float b1v[8], b2v[8];
#pragma unroll
  for (int nt = 0; nt < 8; ++nt) {
    b1v[nt] = b1[nt * 16 + ln] * LOG2E;
    b2v[nt] = b2[nt * 16 + ln];
  }
  __syncthreads();  // the only barrier; hbuf use below is wave-private

  short (*band)[128] = &hbuf[wv * 16];

  for (int tile = blockIdx.x; tile < NTILES; tile += gridDim.x) {
    const int atom = tile * WAVES + wv;
    const int prow = atom * NB;
    const int* nbp = nbr + prow;

    float o0 = 0.f, o1 = 0.f;

#pragma unroll
    for (int mt = 0; mt < 2; ++mt) {
      // ---- rbf A-frags for this 16-row half (nontemporal: streamed once) ----
      const float* src = rbf + (prow + mt * 16 + ln) * RD + q * 8;
      short8 afrag[2];
#pragma unroll
      for (int kt = 0; kt < 2; ++kt) {
        floatx4 lo = __builtin_nontemporal_load((const floatx4*)(src + kt * 32));
        floatx4 hi = __builtin_nontemporal_load((const floatx4*)(src + kt * 32 + 4));
        union { short8 s8; unsigned u[4]; } f;
        f.u[0] = pk2(lo[0], lo[1]);
        f.u[1] = pk2(lo[2], lo[3]);
        f.u[2] = pk2(hi[0], hi[1]);
        f.u[3] = pk2(hi[2], hi[3]);
        afrag[kt] = f.s8;
      }

      // ---- GEMM1: acc = rbf @ w1' + b1' (bias in acc init), K=64 ----
      floatx4 acc[8];
#pragma unroll
      for (int nt = 0; nt < 8; ++nt)
        acc[nt] = floatx4{b1v[nt], b1v[nt], b1v[nt], b1v[nt]};
#pragma unroll
      for (int kt = 0; kt < 2; ++kt)
#pragma unroll
        for (int nt = 0; nt < 8; ++nt) {
          short8 bfrag = *(const short8*)&w1f[kt * 8 + nt][lane][0];
          acc[nt] = __builtin_amdgcn_mfma_f32_16x16x32_bf16(
              afrag[kt], bfrag, acc[nt], 0, 0, 0);
        }

      // ---- H' = log2(1+2^acc) -> bf16 -> swizzled band (C-layout) ----
#pragma unroll
      for (int nt = 0; nt < 8; ++nt) {
        const int c  = nt * 16 + ln;
        const int cb = c >> 3, cl = c & 7;
        unsigned u01 = pk2(sp2(acc[nt][0]), sp2(acc[nt][1]));
        unsigned u23 = pk2(sp2(acc[nt][2]), sp2(acc[nt][3]));
        band[q * 4 + 0][(((cb ^ (q * 4 + 0)) & 15) << 3) | cl] = (short)u01;
        band[q * 4 + 1][(((cb ^ (q * 4 + 1)) & 15) << 3) | cl] = (short)(u01 >> 16);
        band[q * 4 + 2][(((cb ^ (q * 4 + 2)) & 15) << 3) | cl] = (short)u23;
        band[q * 4 + 3][(((cb ^ (q * 4 + 3)) & 15) << 3) | cl] = (short)(u23 >> 16);
      }
      LDS_FENCE();  // H writes must precede hfrag reads in program order

      // ---- H A-frags from band: row=ln, cols kt*32+q*8..+7 (b128, swizzled) ----
      short8 hfrag[4];
#pragma unroll
      for (int kt = 0; kt < 4; ++kt) {
        const int pb = ((kt * 4 + q) ^ ln) & 15;
        hfrag[kt] = *(const short8*)&band[ln][pb << 3];
      }
      LDS_FENCE();  // hfrag reads must precede next half's H writes

      // ---- neighbor indices for this lane's 4 C-rows (issue early) ----
      int j0 = nbp[mt * 16 + q * 4 + 0];   // quad-uniform -> L1 broadcast
      int j1 = nbp[mt * 16 + q * 4 + 1];
      int j2 = nbp[mt * 16 + q * 4 + 2];
      int j3 = nbp[mt * 16 + q * 4 + 3];

      // ---- GEMM2: W = H' @ (ln2*w2) + b2 (bias in acc init), K=128 ----
#pragma unroll
      for (int nt = 0; nt < 8; ++nt)
        acc[nt] = floatx4{b2v[nt], b2v[nt], b2v[nt], b2v[nt]};
#pragma unroll
      for (int kt = 0; kt < 4; ++kt)
#pragma unroll
        for (int nt = 0; nt < 8; ++nt) {
          short8 bfrag = *(const short8*)&w2f[kt * 8 + nt][lane][0];
          acc[nt] = __builtin_amdgcn_mfma_f32_16x16x32_bf16(
              hfrag[kt], bfrag, acc[nt], 0, 0, 0);
        }

      // ---- epilogue in C-layout: lane owns rows q*4+r, cols nt*16+ln ----
      // x row reads: per (r,nt) instr, 16 lanes (ln) read 64B segments.
      float psum[8];
#pragma unroll
      for (int nt = 0; nt < 8; ++nt) psum[nt] = 0.f;
      {
        const float* xr0 = x + (size_t)j0 * FD + ln;
        const float* xr1 = x + (size_t)j1 * FD + ln;
        const float* xr2 = x + (size_t)j2 * FD + ln;
        const float* xr3 = x + (size_t)j3 * FD + ln;
#pragma unroll
        for (int nt = 0; nt < 8; ++nt) {
          psum[nt] = fmaf(xr0[nt * 16], acc[nt][0], psum[nt]);
          psum[nt] = fmaf(xr1[nt * 16], acc[nt][1], psum[nt]);
          psum[nt] = fmaf(xr2[nt * 16], acc[nt][2], psum[nt]);
          psum[nt] = fmaf(xr3[nt * 16], acc[nt][3], psum[nt]);
        }
      }
      // reduce over the 4 row-quads (lane bits 4,5); fold into o0/o1 per half
#pragma unroll
      for (int nt = 0; nt < 8; ++nt) {
        psum[nt] += __shfl_xor(psum[nt], 16);
        psum[nt] += __shfl_xor(psum[nt], 32);
      }
      o0 += (q == 0) ? psum[0] : (q == 1) ? psum[2] : (q == 2) ? psum[4] : psum[6];
      o1 += (q == 0) ? psum[1] : (q == 1) ? psum[3] : (q == 2) ? psum[5] : psum[7];
    }

    // lane (q,ln) writes f = q*32+ln and q*32+16+ln: coalesced 256B per instr
    float* op = out + atom * FD + q * 32 + ln;
    __builtin_nontemporal_store(o0, op);
    __builtin_nontemporal_store(o1, op + 16);
  }
}

extern "C" void kernel_launch(void* const* d_in, const int* in_sizes, int n_in,
                              void* d_out, int out_size, void* d_ws, size_t ws_size,
                              hipStream_t stream) {
  const float* x   = (const float*)d_in[0];
  const float* rbf = (const float*)d_in[1];
  const int*   nbr = (const int*)d_in[2];
  const float* w1  = (const float*)d_in[3];
  const float* b1  = (const float*)d_in[4];
  const float* w2  = (const float*)d_in[5];
  const float* b2  = (const float*)d_in[6];
  float* out = (float*)d_out;

  // 80 KB LDS -> 2 blocks/CU. 500 blocks x 5 tiles each: exact, all co-resident.
  cfconv_kernel<<<dim3(500), dim3(512), 0, stream>>>(x, rbf, nbr, w1, b1, w2, b2, out);
}